// Round 4
// baseline (1164.466 us; speedup 1.0000x reference)
//
#include <hip/hip_runtime.h>
#include <hip/hip_bf16.h>
#include <stdint.h>

#define BB 4
#define SS 2048
#define DD 2048
#define HH 16
#define HD 128
#define MTOT (BB*SS)   // 8192 rows for both big GEMMs

typedef __attribute__((ext_vector_type(8))) short short8;   // 8 bf16 (4 VGPRs)
typedef __attribute__((ext_vector_type(4))) float f32x4;    // MFMA C/D

__device__ __forceinline__ unsigned short f2bf(float f) {
    union { float f; unsigned int u; } v; v.f = f;
    unsigned int u = v.u;
    return (unsigned short)((u + 0x7FFFu + ((u >> 16) & 1u)) >> 16);  // RNE
}

// ---------------------------------------------------------------- converts
__global__ __launch_bounds__(256) void convert_kernel(
    const float* __restrict__ src, unsigned short* __restrict__ dst, int n4) {
    int i = blockIdx.x * 256 + threadIdx.x;
    if (i >= n4) return;
    float4 v = ((const float4*)src)[i];
    unsigned int lo = (unsigned int)f2bf(v.x) | ((unsigned int)f2bf(v.y) << 16);
    unsigned int hi = (unsigned int)f2bf(v.z) | ((unsigned int)f2bf(v.w) << 16);
    ((uint2*)dst)[i] = make_uint2(lo, hi);
}

// RoPE on query + bf16 convert. One thread per (even,odd) pair.
__global__ __launch_bounds__(256) void rope_q_kernel(
    const float* __restrict__ q, const float* __restrict__ fc,
    const float* __restrict__ fs, unsigned short* __restrict__ dst) {
    int idx = blockIdx.x * 256 + threadIdx.x;          // pair index, 0..B*S*D/2
    int row   = idx >> 10;                             // b*S + s
    int s     = row & (SS - 1);
    int p     = idx & 63;                              // pos within head /2
    float2 t = ((const float2*)q)[idx];
    float c = fc[s*64 + p], sn = fs[s*64 + p];
    float o1 = t.x*c - t.y*sn;
    float o2 = t.x*sn + t.y*c;
    ((unsigned int*)dst)[idx] = (unsigned int)f2bf(o1) | ((unsigned int)f2bf(o2) << 16);
}

// value (B,S,H,HD) fp32 -> Vt (B,H,HD,S) bf16. 64(s) x 64(d) LDS tile per block.
__global__ __launch_bounds__(256) void transpose_v_kernel(
    const float* __restrict__ v, unsigned short* __restrict__ vt) {
    __shared__ unsigned short tile[64][72];
    int bh = blockIdx.z;                   // b*16 + h
    int s0 = blockIdx.x * 64, d0 = blockIdx.y * 64;
    int t = threadIdx.x;
    #pragma unroll
    for (int it = 0; it < 4; ++it) {
        int i  = it*16 + (t >> 4);         // local s
        int j4 = t & 15;                   // float4 index along d
        float4 f = *(const float4*)(v +
            (((size_t)((bh >> 4)*SS + s0 + i)*HH + (bh & 15))*HD + d0 + j4*4));
        unsigned int lo = (unsigned int)f2bf(f.x) | ((unsigned int)f2bf(f.y) << 16);
        unsigned int hi = (unsigned int)f2bf(f.z) | ((unsigned int)f2bf(f.w) << 16);
        *(uint2*)&tile[i][j4*4] = make_uint2(lo, hi);
    }
    __syncthreads();
    unsigned int* vt32 = (unsigned int*)vt;
    #pragma unroll
    for (int it = 0; it < 8; ++it) {
        int task = it*256 + t;
        int sp = task & 31;                // s-pair within tile
        int d  = task >> 5;                // local d, 0..63
        unsigned int lo = tile[2*sp][d], hi = tile[2*sp + 1][d];
        vt32[((size_t)bh*HD + d0 + d)*(SS/2) + (s0 >> 1) + sp] = lo | (hi << 16);
    }
}

// ---------------------------------------------------------------- GEMM
// C[m,n] = sum_k A[m,k]*W[n,k] + bias[n].  A: MxK bf16 row-major, W: NxK bf16.
// MODE 0: fused RoPE epilogue, bf16 out (K projection).
// MODE 1: plain epilogue, fp32 out (output projection).
template<int MODE>
__global__ __launch_bounds__(256, 2) void gemm_kernel(
    const unsigned short* __restrict__ A, const unsigned short* __restrict__ W,
    const float* __restrict__ bias, const float* __restrict__ fc,
    const float* __restrict__ fs, void* __restrict__ out)
{
    __shared__ unsigned short As[128*32];
    __shared__ unsigned short Bs[128*32];
    const int K = DD;
    int m0 = blockIdx.y * 128, n0 = blockIdx.x * 128;
    int t = threadIdx.x, lane = t & 63, w = t >> 6;
    int wm = w >> 1, wn = w & 1;
    int l15 = lane & 15, quad = lane >> 4;

    f32x4 acc[4][4] = {};

    for (int k0 = 0; k0 < K; k0 += 32) {
        __syncthreads();                    // prior tile's LDS reads done
        #pragma unroll
        for (int i = 0; i < 2; ++i) {
            int ci  = i*256 + t;            // 16B chunk id, 0..511
            int row = ci >> 2;
            int ce  = (ci & 3) * 8;         // elem offset within 32-col row
            const unsigned short* ga = A + (size_t)(m0 + row) * K + k0 + ce;
            const unsigned short* gb = W + (size_t)(n0 + row) * K + k0 + ce;
            unsigned short* la = As + (size_t)(i*256 + w*64) * 8;  // wave-uniform
            unsigned short* lb = Bs + (size_t)(i*256 + w*64) * 8;
            __builtin_amdgcn_global_load_lds(
                (__attribute__((address_space(1))) void*)(uintptr_t)ga,
                (__attribute__((address_space(3))) void*)la, 16, 0, 0);
            __builtin_amdgcn_global_load_lds(
                (__attribute__((address_space(1))) void*)(uintptr_t)gb,
                (__attribute__((address_space(3))) void*)lb, 16, 0, 0);
        }
        __syncthreads();                    // drains vmcnt (global_load_lds)

        short8 af[4], bw[4];
        #pragma unroll
        for (int i = 0; i < 4; ++i) {
            af[i] = *(const short8*)(As + (size_t)(wm*64 + i*16 + l15)*32 + quad*8);
            bw[i] = *(const short8*)(Bs + (size_t)(wn*64 + i*16 + l15)*32 + quad*8);
        }
        #pragma unroll
        for (int i = 0; i < 4; ++i)
            #pragma unroll
            for (int j = 0; j < 4; ++j)
                acc[i][j] = __builtin_amdgcn_mfma_f32_16x16x32_bf16(
                    af[i], bw[j], acc[i][j], 0, 0, 0);
    }

    // epilogue: C/D layout col=lane&15, row=quad*4+reg  [m89-verified]
    #pragma unroll
    for (int i = 0; i < 4; ++i) {
        #pragma unroll
        for (int j = 0; j < 4; ++j) {
            int col = n0 + wn*64 + j*16 + l15;
            float bv = bias[col];
            #pragma unroll
            for (int r = 0; r < 4; ++r) {
                int row = m0 + wm*64 + i*16 + quad*4 + r;
                float v = acc[i][j][r] + bv;
                if (MODE == 0) {
                    // fused RoPE: pair partner is the adjacent lane (col parity = lane parity)
                    int s = row & (SS - 1);
                    int p = (col & 127) >> 1;
                    float other = __shfl_xor(v, 1);
                    float c = fc[s*64 + p], sn = fs[s*64 + p];
                    float res = (col & 1) ? (other*sn + v*c) : (v*c - other*sn);
                    ((unsigned short*)out)[(size_t)row*DD + col] = f2bf(res);
                } else {
                    ((float*)out)[(size_t)row*DD + col] = v;
                }
            }
        }
    }
}

// ---------------------------------------------------------------- attention
// Flash-style causal attention, BARRIER-FREE. Block = 4 independent waves;
// wave w owns q-rows [q0+16w, q0+16w+16). All K/V/Q fragments are 16B-
// contiguous in global memory and load directly into VGPRs (no LDS staging,
// no __syncthreads anywhere). Only LDS use: Ps (C->A layout round-trip),
// wave-private rows. Q,Kr (B,S,H,HD) roped bf16; Vt (B,H,HD,S) bf16.
__global__ __launch_bounds__(256, 3) void attn_kernel(
    const unsigned short* __restrict__ Q, const unsigned short* __restrict__ Kr,
    const unsigned short* __restrict__ Vt, unsigned short* __restrict__ O)
{
    constexpr int PSTR = 72;
    __shared__ unsigned short Ps[64*PSTR];   // rows [16w,16w+16) private to wave w

    int bh = blockIdx.y;
    int b = bh >> 4, h = bh & 15;
    size_t base  = (size_t)b*SS*DD + (size_t)h*HD;   // Q/K/O: + s*DD + d
    size_t vbase = (size_t)bh*HD*SS;                 // Vt: + d*SS + s

    int t = threadIdx.x, lane = t & 63, w = t >> 6;
    int l15 = lane & 15, quad = lane >> 4;
    int pair = blockIdx.x;                           // 0..15

    // scores scaled by 1/sqrt(128)*log2(e) so softmax uses exp2 directly
    const float scl2 = 0.08838834764831845f * 1.44269504088896f;

    for (int ph = 0; ph < 2; ++ph) {
        int qt = ph ? (31 - pair) : pair;            // iters: (pair+1)+(32-pair)=33
        int q0 = qt * 64;

        // A-fragment of Q: m=l15 row, k=quad*8+j offset — 16B contiguous.
        short8 aq[4];
        #pragma unroll
        for (int kk = 0; kk < 4; ++kk)
            aq[kk] = *(const short8*)(Q + base +
                (size_t)(q0 + w*16 + l15)*DD + kk*32 + quad*8);

        float m_i[4], l_i[4];
        #pragma unroll
        for (int r = 0; r < 4; ++r) { m_i[r] = -1e30f; l_i[r] = 0.f; }
        f32x4 o_acc[8] = {};

        for (int jt = 0; jt <= qt; ++jt) {
            int j0 = jt * 64;

            // QK^T: B-fragment of K rows direct from global (16B each)
            f32x4 sacc[4];
            #pragma unroll
            for (int c = 0; c < 4; ++c) {
                const unsigned short* kp =
                    Kr + base + (size_t)(j0 + c*16 + l15)*DD + quad*8;
                sacc[c] = (f32x4){0.f, 0.f, 0.f, 0.f};
                #pragma unroll
                for (int kk = 0; kk < 4; ++kk) {
                    short8 bk = *(const short8*)(kp + kk*32);
                    sacc[c] = __builtin_amdgcn_mfma_f32_16x16x32_bf16(aq[kk], bk, sacc[c], 0,0,0);
                }
            }

            // scale(log2e folded) + causal mask + online softmax (base-2)
            bool diag = (jt == qt);
            float p[4][4], mt[4];
            #pragma unroll
            for (int r = 0; r < 4; ++r) mt[r] = -1e30f;
            #pragma unroll
            for (int c = 0; c < 4; ++c)
                #pragma unroll
                for (int r = 0; r < 4; ++r) {
                    float v = sacc[c][r] * scl2;
                    if (diag) {
                        int cg = c*16 + l15;              // col offset in tile
                        int rg = w*16 + quad*4 + r;       // row offset (j0==q0)
                        if (cg > rg) v = -1e30f;
                    }
                    p[c][r] = v;
                    mt[r] = fmaxf(mt[r], v);
                }
            #pragma unroll
            for (int r = 0; r < 4; ++r) {       // row-max across the 16 quad lanes
                float m = mt[r];
                m = fmaxf(m, __shfl_xor(m, 1));
                m = fmaxf(m, __shfl_xor(m, 2));
                m = fmaxf(m, __shfl_xor(m, 4));
                m = fmaxf(m, __shfl_xor(m, 8));
                float mnew = fmaxf(m_i[r], m);
                mt[r] = exp2f(m_i[r] - mnew);   // alpha
                m_i[r] = mnew;
            }
            float rs[4] = {0.f, 0.f, 0.f, 0.f};
            #pragma unroll
            for (int c = 0; c < 4; ++c)
                #pragma unroll
                for (int r = 0; r < 4; ++r) {
                    float e = exp2f(p[c][r] - m_i[r]);
                    p[c][r] = e;
                    rs[r] += e;
                }
            #pragma unroll
            for (int r = 0; r < 4; ++r) {
                float s = rs[r];
                s += __shfl_xor(s, 1);
                s += __shfl_xor(s, 2);
                s += __shfl_xor(s, 4);
                s += __shfl_xor(s, 8);
                l_i[r] = l_i[r]*mt[r] + s;
            }
            #pragma unroll
            for (int f = 0; f < 8; ++f)
                #pragma unroll
                for (int r = 0; r < 4; ++r)
                    o_acc[f][r] *= mt[r];

            // P: C-layout -> LDS -> A-layout. Wave-private rows; same-wave
            // DS ops execute in order — no barrier needed.
            #pragma unroll
            for (int c = 0; c < 4; ++c)
                #pragma unroll
                for (int r = 0; r < 4; ++r)
                    Ps[(size_t)(w*16 + quad*4 + r)*PSTR + c*16 + l15] = f2bf(p[c][r]);

            // PV: B-fragment of Vt rows direct from global (16B each)
            #pragma unroll
            for (int kk2 = 0; kk2 < 2; ++kk2) {
                short8 ap = *(const short8*)(Ps + (size_t)(w*16 + l15)*PSTR + kk2*32 + quad*8);
                #pragma unroll
                for (int f = 0; f < 8; ++f) {
                    short8 bv = *(const short8*)(Vt + vbase +
                        (size_t)(f*16 + l15)*SS + j0 + kk2*32 + quad*8);
                    o_acc[f] = __builtin_amdgcn_mfma_f32_16x16x32_bf16(ap, bv, o_acc[f], 0,0,0);
                }
            }
        }

        // epilogue: normalize and store bf16 (B,S,H,HD)
        #pragma unroll
        for (int f = 0; f < 8; ++f) {
            #pragma unroll
            for (int r = 0; r < 4; ++r) {
                int srow = q0 + w*16 + quad*4 + r;
                int d = f*16 + l15;
                O[base + (size_t)srow*DD + d] = f2bf(o_acc[f][r] / l_i[r]);
            }
        }
    }
}

// ---------------------------------------------------------------- launch
extern "C" void kernel_launch(void* const* d_in, const int* in_sizes, int n_in,
                              void* d_out, int out_size, void* d_ws, size_t ws_size,
                              hipStream_t stream) {
    const float* x      = (const float*)d_in[0];
    const float* query  = (const float*)d_in[1];
    const float* value  = (const float*)d_in[2];
    const float* fc     = (const float*)d_in[3];
    const float* fs     = (const float*)d_in[4];
    const float* key_w  = (const float*)d_in[5];
    const float* key_b  = (const float*)d_in[6];
    const float* proj_w = (const float*)d_in[7];
    const float* proj_b = (const float*)d_in[8];

    const int ND  = BB*SS*DD;      // 16777216
    const int NW  = DD*DD;         // 4194304
    unsigned short* xb  = (unsigned short*)d_ws;   // x bf16
    unsigned short* kwb = xb  + ND;                // key_w bf16
    unsigned short* pwb = kwb + NW;                // proj_w bf16
    unsigned short* qr  = pwb + NW;                // query roped bf16
    unsigned short* vt  = qr  + ND;                // value transposed (B,H,HD,S) bf16
    unsigned short* kr  = vt  + ND;                // k projected+roped bf16
    unsigned short* ao  = xb;                      // attn out reuses x region

    convert_kernel<<<ND/4/256, 256, 0, stream>>>(x, xb, ND/4);
    convert_kernel<<<NW/4/256, 256, 0, stream>>>(key_w, kwb, NW/4);
    convert_kernel<<<NW/4/256, 256, 0, stream>>>(proj_w, pwb, NW/4);
    rope_q_kernel<<<ND/2/256, 256, 0, stream>>>(query, fc, fs, qr);
    transpose_v_kernel<<<dim3(SS/64, HD/64, BB*HH), 256, 0, stream>>>(value, vt);

    dim3 gg(DD/128, MTOT/128);     // 16 x 64
    gemm_kernel<0><<<gg, 256, 0, stream>>>(xb, kwb, key_b, fc, fs, (void*)kr);
    attn_kernel<<<dim3(16, BB*HH), 256, 0, stream>>>(qr, kr, vt, ao);
    gemm_kernel<1><<<gg, 256, 0, stream>>>(ao, pwb, proj_b, nullptr, nullptr, d_out);
}

// Round 5
// 649.602 us; speedup vs baseline: 1.7926x; 1.7926x over previous
//
#include <hip/hip_runtime.h>
#include <hip/hip_bf16.h>
#include <stdint.h>

#define BB 4
#define SS 2048
#define DD 2048
#define HH 16
#define HD 128
#define MTOT (BB*SS)   // 8192 rows for both big GEMMs

typedef __attribute__((ext_vector_type(8))) short short8;   // 8 bf16 (4 VGPRs)
typedef __attribute__((ext_vector_type(4))) float f32x4;    // MFMA C/D

__device__ __forceinline__ unsigned short f2bf(float f) {
    union { float f; unsigned int u; } v; v.f = f;
    unsigned int u = v.u;
    return (unsigned short)((u + 0x7FFFu + ((u >> 16) & 1u)) >> 16);  // RNE
}

// ---------------------------------------------------------------- converts
__global__ __launch_bounds__(256) void convert_kernel(
    const float* __restrict__ src, unsigned short* __restrict__ dst, int n4) {
    int i = blockIdx.x * 256 + threadIdx.x;
    if (i >= n4) return;
    float4 v = ((const float4*)src)[i];
    unsigned int lo = (unsigned int)f2bf(v.x) | ((unsigned int)f2bf(v.y) << 16);
    unsigned int hi = (unsigned int)f2bf(v.z) | ((unsigned int)f2bf(v.w) << 16);
    ((uint2*)dst)[i] = make_uint2(lo, hi);
}

// RoPE on query + bf16 convert. One thread per (even,odd) pair.
__global__ __launch_bounds__(256) void rope_q_kernel(
    const float* __restrict__ q, const float* __restrict__ fc,
    const float* __restrict__ fs, unsigned short* __restrict__ dst) {
    int idx = blockIdx.x * 256 + threadIdx.x;          // pair index, 0..B*S*D/2
    int row   = idx >> 10;                             // b*S + s
    int s     = row & (SS - 1);
    int p     = idx & 63;                              // pos within head /2
    float2 t = ((const float2*)q)[idx];
    float c = fc[s*64 + p], sn = fs[s*64 + p];
    float o1 = t.x*c - t.y*sn;
    float o2 = t.x*sn + t.y*c;
    ((unsigned int*)dst)[idx] = (unsigned int)f2bf(o1) | ((unsigned int)f2bf(o2) << 16);
}

// value (B,S,H,HD) fp32 -> Vt (B,H,HD,S) bf16. 64(s) x 64(d) LDS tile per block.
__global__ __launch_bounds__(256) void transpose_v_kernel(
    const float* __restrict__ v, unsigned short* __restrict__ vt) {
    __shared__ unsigned short tile[64][72];
    int bh = blockIdx.z;                   // b*16 + h
    int s0 = blockIdx.x * 64, d0 = blockIdx.y * 64;
    int t = threadIdx.x;
    #pragma unroll
    for (int it = 0; it < 4; ++it) {
        int i  = it*16 + (t >> 4);         // local s
        int j4 = t & 15;                   // float4 index along d
        float4 f = *(const float4*)(v +
            (((size_t)((bh >> 4)*SS + s0 + i)*HH + (bh & 15))*HD + d0 + j4*4));
        unsigned int lo = (unsigned int)f2bf(f.x) | ((unsigned int)f2bf(f.y) << 16);
        unsigned int hi = (unsigned int)f2bf(f.z) | ((unsigned int)f2bf(f.w) << 16);
        *(uint2*)&tile[i][j4*4] = make_uint2(lo, hi);
    }
    __syncthreads();
    unsigned int* vt32 = (unsigned int*)vt;
    #pragma unroll
    for (int it = 0; it < 8; ++it) {
        int task = it*256 + t;
        int sp = task & 31;                // s-pair within tile
        int d  = task >> 5;                // local d, 0..63
        unsigned int lo = tile[2*sp][d], hi = tile[2*sp + 1][d];
        vt32[((size_t)bh*HD + d0 + d)*(SS/2) + (s0 >> 1) + sp] = lo | (hi << 16);
    }
}

// ---------------------------------------------------------------- GEMM
// C[m,n] = sum_k A[m,k]*W[n,k] + bias[n].  A: MxK bf16 row-major, W: NxK bf16.
// MODE 0: fused RoPE epilogue, bf16 out (K projection).
// MODE 1: plain epilogue, fp32 out (output projection).
template<int MODE>
__global__ __launch_bounds__(256, 2) void gemm_kernel(
    const unsigned short* __restrict__ A, const unsigned short* __restrict__ W,
    const float* __restrict__ bias, const float* __restrict__ fc,
    const float* __restrict__ fs, void* __restrict__ out)
{
    __shared__ unsigned short As[128*32];
    __shared__ unsigned short Bs[128*32];
    const int K = DD;
    int m0 = blockIdx.y * 128, n0 = blockIdx.x * 128;
    int t = threadIdx.x, lane = t & 63, w = t >> 6;
    int wm = w >> 1, wn = w & 1;
    int l15 = lane & 15, quad = lane >> 4;

    f32x4 acc[4][4] = {};

    for (int k0 = 0; k0 < K; k0 += 32) {
        __syncthreads();                    // prior tile's LDS reads done
        #pragma unroll
        for (int i = 0; i < 2; ++i) {
            int ci  = i*256 + t;            // 16B chunk id, 0..511
            int row = ci >> 2;
            int ce  = (ci & 3) * 8;         // elem offset within 32-col row
            const unsigned short* ga = A + (size_t)(m0 + row) * K + k0 + ce;
            const unsigned short* gb = W + (size_t)(n0 + row) * K + k0 + ce;
            unsigned short* la = As + (size_t)(i*256 + w*64) * 8;  // wave-uniform
            unsigned short* lb = Bs + (size_t)(i*256 + w*64) * 8;
            __builtin_amdgcn_global_load_lds(
                (__attribute__((address_space(1))) void*)(uintptr_t)ga,
                (__attribute__((address_space(3))) void*)la, 16, 0, 0);
            __builtin_amdgcn_global_load_lds(
                (__attribute__((address_space(1))) void*)(uintptr_t)gb,
                (__attribute__((address_space(3))) void*)lb, 16, 0, 0);
        }
        __syncthreads();                    // drains vmcnt (global_load_lds)

        short8 af[4], bw[4];
        #pragma unroll
        for (int i = 0; i < 4; ++i) {
            af[i] = *(const short8*)(As + (size_t)(wm*64 + i*16 + l15)*32 + quad*8);
            bw[i] = *(const short8*)(Bs + (size_t)(wn*64 + i*16 + l15)*32 + quad*8);
        }
        #pragma unroll
        for (int i = 0; i < 4; ++i)
            #pragma unroll
            for (int j = 0; j < 4; ++j)
                acc[i][j] = __builtin_amdgcn_mfma_f32_16x16x32_bf16(
                    af[i], bw[j], acc[i][j], 0, 0, 0);
    }

    // epilogue: C/D layout col=lane&15, row=quad*4+reg  [m89-verified]
    #pragma unroll
    for (int i = 0; i < 4; ++i) {
        #pragma unroll
        for (int j = 0; j < 4; ++j) {
            int col = n0 + wn*64 + j*16 + l15;
            float bv = bias[col];
            #pragma unroll
            for (int r = 0; r < 4; ++r) {
                int row = m0 + wm*64 + i*16 + quad*4 + r;
                float v = acc[i][j][r] + bv;
                if (MODE == 0) {
                    // fused RoPE: pair partner is the adjacent lane (col parity = lane parity)
                    int s = row & (SS - 1);
                    int p = (col & 127) >> 1;
                    float other = __shfl_xor(v, 1);
                    float c = fc[s*64 + p], sn = fs[s*64 + p];
                    float res = (col & 1) ? (other*sn + v*c) : (v*c - other*sn);
                    ((unsigned short*)out)[(size_t)row*DD + col] = f2bf(res);
                } else {
                    ((float*)out)[(size_t)row*DD + col] = v;
                }
            }
        }
    }
}

// ---------------------------------------------------------------- attention
// Flash-style causal attention. Block = 4 waves; wave w owns 16 q-rows.
// K/V tiles staged into LDS via async global_load_lds (m97 pattern).
// LDS rows are UNPADDED (wave-uniform-base constraint); bank conflicts
// avoided by an XOR chunk swizzle applied on the GLOBAL side:
//   LDS[row][cc] holds GLOBAL[row][cc ^ (row&7)]  (16B chunks)
// so fragment reads use chunk (g ^ (row&7)) — exact inverse, and the
// resulting ds_read_b128 pattern spreads 8 lanes per 4-bank group (optimal).
// Q fragments load direct from global (read once per phase; R4-verified).
// Pairing: block handles q-tiles (pair, 31-pair) -> uniform 33 iterations.
__global__ __launch_bounds__(256, 3) void attn_kernel(
    const unsigned short* __restrict__ Q, const unsigned short* __restrict__ Kr,
    const unsigned short* __restrict__ Vt, unsigned short* __restrict__ O)
{
    constexpr int PSTR = 72;
    __shared__ unsigned short Ks[64*128];    // K tile, swizzled chunks
    __shared__ unsigned short VTs[128*64];   // Vt tile [d][s], swizzled chunks
    __shared__ unsigned short Ps[64*PSTR];   // rows [16w,16w+16) private to wave w

    int bh = blockIdx.y;
    int b = bh >> 4, h = bh & 15;
    size_t base  = (size_t)b*SS*DD + (size_t)h*HD;   // Q/K/O: + s*DD + d
    size_t vbase = (size_t)bh*HD*SS;                 // Vt: + d*SS + s

    int t = threadIdx.x, lane = t & 63, w = t >> 6;
    int l15 = lane & 15, quad = lane >> 4;
    int pair = blockIdx.x;                           // 0..15
    int l7 = l15 & 7;

    // scores scaled by 1/sqrt(128)*log2(e) so softmax uses exp2 directly
    const float scl2 = 0.08838834764831845f * 1.44269504088896f;

    for (int ph = 0; ph < 2; ++ph) {
        int qt = ph ? (31 - pair) : pair;            // iters: (pair+1)+(32-pair)=33
        int q0 = qt * 64;

        // A-fragment of Q direct from global: m=l15 row, k=quad*8+j offset.
        short8 aq[4];
        #pragma unroll
        for (int kk = 0; kk < 4; ++kk)
            aq[kk] = *(const short8*)(Q + base +
                (size_t)(q0 + w*16 + l15)*DD + kk*32 + quad*8);

        float m_i[4], l_i[4];
        #pragma unroll
        for (int r = 0; r < 4; ++r) { m_i[r] = -1e30f; l_i[r] = 0.f; }
        f32x4 o_acc[8] = {};

        for (int jt = 0; jt <= qt; ++jt) {
            int j0 = jt * 64;

            __syncthreads();               // WAR: prior tile's Ks/VTs reads done
            // stage K tile 64x128: 1024 chunks, 4 glds per thread
            #pragma unroll
            for (int i = 0; i < 4; ++i) {
                int ci  = i*256 + t;
                int row = ci >> 4;                 // 0..63
                int cc  = ci & 15;                 // LDS chunk within row
                int gch = cc ^ (row & 7);          // global chunk (swizzle)
                const unsigned short* ga =
                    Kr + base + (size_t)(j0 + row)*DD + gch*8;
                unsigned short* la = Ks + (size_t)(i*256 + w*64) * 8;  // wave-uniform
                __builtin_amdgcn_global_load_lds(
                    (__attribute__((address_space(1))) void*)(uintptr_t)ga,
                    (__attribute__((address_space(3))) void*)la, 16, 0, 0);
            }
            // stage V tile 128x64: 1024 chunks, 4 glds per thread
            #pragma unroll
            for (int i = 0; i < 4; ++i) {
                int ci  = i*256 + t;
                int d   = ci >> 3;                 // 0..127
                int cc  = ci & 7;
                int gch = cc ^ (d & 7);
                const unsigned short* ga =
                    Vt + vbase + (size_t)d*SS + j0 + gch*8;
                unsigned short* la = VTs + (size_t)(i*256 + w*64) * 8;
                __builtin_amdgcn_global_load_lds(
                    (__attribute__((address_space(1))) void*)(uintptr_t)ga,
                    (__attribute__((address_space(3))) void*)la, 16, 0, 0);
            }
            __syncthreads();               // RAW: drains vmcnt

            // QK^T: wave's 16 q-rows x 64 k-cols
            f32x4 sacc[4];
            #pragma unroll
            for (int c = 0; c < 4; ++c) {
                sacc[c] = (f32x4){0.f, 0.f, 0.f, 0.f};
                #pragma unroll
                for (int kk = 0; kk < 4; ++kk) {
                    short8 bk = *(const short8*)(Ks +
                        (size_t)(c*16 + l15)*128 + ((kk*4 + quad) ^ l7)*8);
                    sacc[c] = __builtin_amdgcn_mfma_f32_16x16x32_bf16(aq[kk], bk, sacc[c], 0,0,0);
                }
            }

            // scale(log2e folded) + causal mask + online softmax (base-2)
            bool diag = (jt == qt);
            float p[4][4], mt[4];
            #pragma unroll
            for (int r = 0; r < 4; ++r) mt[r] = -1e30f;
            #pragma unroll
            for (int c = 0; c < 4; ++c)
                #pragma unroll
                for (int r = 0; r < 4; ++r) {
                    float v = sacc[c][r] * scl2;
                    if (diag) {
                        int cg = c*16 + l15;              // col offset in tile
                        int rg = w*16 + quad*4 + r;       // row offset (j0==q0)
                        if (cg > rg) v = -1e30f;
                    }
                    p[c][r] = v;
                    mt[r] = fmaxf(mt[r], v);
                }
            #pragma unroll
            for (int r = 0; r < 4; ++r) {       // row-max across the 16 quad lanes
                float m = mt[r];
                m = fmaxf(m, __shfl_xor(m, 1));
                m = fmaxf(m, __shfl_xor(m, 2));
                m = fmaxf(m, __shfl_xor(m, 4));
                m = fmaxf(m, __shfl_xor(m, 8));
                float mnew = fmaxf(m_i[r], m);
                mt[r] = exp2f(m_i[r] - mnew);   // alpha
                m_i[r] = mnew;
            }
            float rs[4] = {0.f, 0.f, 0.f, 0.f};
            #pragma unroll
            for (int c = 0; c < 4; ++c)
                #pragma unroll
                for (int r = 0; r < 4; ++r) {
                    float e = exp2f(p[c][r] - m_i[r]);
                    p[c][r] = e;
                    rs[r] += e;
                }
            #pragma unroll
            for (int r = 0; r < 4; ++r) {
                float s = rs[r];
                s += __shfl_xor(s, 1);
                s += __shfl_xor(s, 2);
                s += __shfl_xor(s, 4);
                s += __shfl_xor(s, 8);
                l_i[r] = l_i[r]*mt[r] + s;
            }
            #pragma unroll
            for (int f = 0; f < 8; ++f)
                #pragma unroll
                for (int r = 0; r < 4; ++r)
                    o_acc[f][r] *= mt[r];

            // P: C-layout -> LDS -> A-layout. Wave-private rows, same-wave
            // DS ordering — no barrier needed (R2/R4-verified).
            #pragma unroll
            for (int c = 0; c < 4; ++c)
                #pragma unroll
                for (int r = 0; r < 4; ++r)
                    Ps[(size_t)(w*16 + quad*4 + r)*PSTR + c*16 + l15] = f2bf(p[c][r]);

            // PV: o += P(16x64) @ V(64x128), V fragments from swizzled VTs
            #pragma unroll
            for (int kk2 = 0; kk2 < 2; ++kk2) {
                short8 ap = *(const short8*)(Ps + (size_t)(w*16 + l15)*PSTR + kk2*32 + quad*8);
                #pragma unroll
                for (int f = 0; f < 8; ++f) {
                    short8 bv = *(const short8*)(VTs +
                        (size_t)(f*16 + l15)*64 + ((kk2*4 + quad) ^ l7)*8);
                    o_acc[f] = __builtin_amdgcn_mfma_f32_16x16x32_bf16(ap, bv, o_acc[f], 0,0,0);
                }
            }
        }

        // epilogue: normalize and store bf16 (B,S,H,HD)
        #pragma unroll
        for (int f = 0; f < 8; ++f) {
            #pragma unroll
            for (int r = 0; r < 4; ++r) {
                int srow = q0 + w*16 + quad*4 + r;
                int d = f*16 + l15;
                O[base + (size_t)srow*DD + d] = f2bf(o_acc[f][r] / l_i[r]);
            }
        }
    }
}

// ---------------------------------------------------------------- launch
extern "C" void kernel_launch(void* const* d_in, const int* in_sizes, int n_in,
                              void* d_out, int out_size, void* d_ws, size_t ws_size,
                              hipStream_t stream) {
    const float* x      = (const float*)d_in[0];
    const float* query  = (const float*)d_in[1];
    const float* value  = (const float*)d_in[2];
    const float* fc     = (const float*)d_in[3];
    const float* fs     = (const float*)d_in[4];
    const float* key_w  = (const float*)d_in[5];
    const float* key_b  = (const float*)d_in[6];
    const float* proj_w = (const float*)d_in[7];
    const float* proj_b = (const float*)d_in[8];

    const int ND  = BB*SS*DD;      // 16777216
    const int NW  = DD*DD;         // 4194304
    unsigned short* xb  = (unsigned short*)d_ws;   // x bf16
    unsigned short* kwb = xb  + ND;                // key_w bf16
    unsigned short* pwb = kwb + NW;                // proj_w bf16
    unsigned short* qr  = pwb + NW;                // query roped bf16
    unsigned short* vt  = qr  + ND;                // value transposed (B,H,HD,S) bf16
    unsigned short* kr  = vt  + ND;                // k projected+roped bf16
    unsigned short* ao  = xb;                      // attn out reuses x region

    convert_kernel<<<ND/4/256, 256, 0, stream>>>(x, xb, ND/4);
    convert_kernel<<<NW/4/256, 256, 0, stream>>>(key_w, kwb, NW/4);
    convert_kernel<<<NW/4/256, 256, 0, stream>>>(proj_w, pwb, NW/4);
    rope_q_kernel<<<ND/2/256, 256, 0, stream>>>(query, fc, fs, qr);
    transpose_v_kernel<<<dim3(SS/64, HD/64, BB*HH), 256, 0, stream>>>(value, vt);

    dim3 gg(DD/128, MTOT/128);     // 16 x 64
    gemm_kernel<0><<<gg, 256, 0, stream>>>(xb, kwb, key_b, fc, fs, (void*)kr);
    attn_kernel<<<dim3(16, BB*HH), 256, 0, stream>>>(qr, kr, vt, ao);
    gemm_kernel<1><<<gg, 256, 0, stream>>>(ao, pwb, proj_b, nullptr, nullptr, d_out);
}